// Round 12
// baseline (1104.000 us; speedup 1.0000x reference)
//
#include <hip/hip_runtime.h>

#define NB 16
#define NPTS 4096
#define NC 64
#define NS 1024
#define NK 32

typedef float v2f __attribute__((ext_vector_type(2)));
typedef short bf16x8 __attribute__((ext_vector_type(8)));
typedef float f32x4 __attribute__((ext_vector_type(4)));

#define DPP_ROR_I(x, N) __builtin_amdgcn_update_dpp(0, (int)(x), 0x120 + (N), 0xf, 0xf, false)
#define MFMA16(a, b, c) __builtin_amdgcn_mfma_f32_16x16x32_bf16((a), (b), (c), 0, 0, 0)

static __device__ __forceinline__ float max3f(float a, float b, float c) {
    return fmaxf(fmaxf(a, b), c);
}
static __device__ __forceinline__ unsigned min3u(unsigned a, unsigned b, unsigned c) {
    const unsigned m = a < b ? a : b;
    return m < c ? m : c;
}
static __device__ __forceinline__ unsigned short f2bf(float f) {
    const unsigned u = __float_as_uint(f);
    const unsigned r = 0x7FFFu + ((u >> 16) & 1u);
    return (unsigned short)((u + r) >> 16);
}
static __device__ __forceinline__ float bf2f(unsigned short h) {
    return __uint_as_float(((unsigned)h) << 16);
}
static __device__ __forceinline__ unsigned pkhi(float a, float b) {
    return (unsigned)f2bf(a) | ((unsigned)f2bf(b) << 16);
}
static __device__ __forceinline__ unsigned pklo(float a, float b) {
    const float la = a - bf2f(f2bf(a));
    const float lb = b - bf2f(f2bf(b));
    return (unsigned)f2bf(la) | ((unsigned)f2bf(lb) << 16);
}

// ---------------------------------------------------------------------------
// FPS: 8 blocks x 512 threads. Waves 0-3 process batch 2b, waves 4-7 batch
// 2b+1 — two INDEPENDENT serial chains per CU (2 waves/SIMD) so one chain's
// post-barrier/reduce stalls are filled by the other's update issue.
// Per-half loop identical to the R10-verified kernel (bit-exact selection).
// LDS: 2x64KB pts + 24KB history + keys = 152.2KB (1 block/CU).
// ---------------------------------------------------------------------------
__global__ __launch_bounds__(512) void fps_kernel(const float* __restrict__ xyz,
                                                  float* __restrict__ out_xyz) {
    __shared__ float4 pts4[2][NPTS];
    __shared__ float hist[2][3][NS];
    __shared__ unsigned wk[2][2][4][2];  // [half][buf][wave4][kh,kl]

    const int t = threadIdx.x;
    const int half = t >> 8;             // 0: waves 0-3, 1: waves 4-7
    const int th = t & 255;              // thread id within half
    const int wv4 = (t >> 6) & 3;
    const int lane = t & 63;
    const int b = blockIdx.x * 2 + half;

    const float* xb = xyz + (size_t)b * NPTS * 3;
    for (int i = th; i < NPTS; i += 256) {
        pts4[half][i] = make_float4(xb[3 * i], xb[3 * i + 1], xb[3 * i + 2], 0.0f);
    }
    __syncthreads();

    v2f PX[8], PY[8], PZ[8];
    float dm[16];
#pragma unroll
    for (int k = 0; k < 8; ++k) {
        const float4 p0 = pts4[half][th + (2 * k) * 256];
        const float4 p1 = pts4[half][th + (2 * k + 1) * 256];
        PX[k].x = p0.x; PX[k].y = p1.x;
        PY[k].x = p0.y; PY[k].y = p1.y;
        PZ[k].x = p0.z; PZ[k].y = p1.z;
        dm[2 * k] = 1e10f; dm[2 * k + 1] = 1e10f;
    }

    const float4 c0 = pts4[half][0];
    float cx = c0.x, cy = c0.y, cz = c0.z;

    for (int s = 0; s < NS; ++s) {
        if (th == 0) { hist[half][0][s] = cx; hist[half][1][s] = cy; hist[half][2][s] = cz; }

        // packed min-dist update (bit-identical per-component arithmetic)
        const v2f cX = { cx, cx };
        const v2f cY = { cy, cy };
        const v2f cZ = { cz, cz };
#pragma unroll
        for (int k = 0; k < 8; ++k) {
            const v2f dX = PX[k] - cX;
            const v2f dY = PY[k] - cY;
            const v2f dZ = PZ[k] - cZ;
            const v2f t1 = dX * dX;
            const v2f t2 = dY * dY;
            const v2f t3 = dZ * dZ;
            const v2f ss = (t1 + t2) + t3;
            dm[2 * k] = fminf(dm[2 * k], ss.x);
            dm[2 * k + 1] = fminf(dm[2 * k + 1], ss.y);
        }

        // lane max via ternary max3 tree
        const float ta = max3f(dm[0], dm[1], dm[2]);
        const float tb = max3f(dm[3], dm[4], dm[5]);
        const float tc = max3f(dm[6], dm[7], dm[8]);
        const float td = max3f(dm[9], dm[10], dm[11]);
        const float te = max3f(dm[12], dm[13], dm[14]);
        const float mv = fmaxf(max3f(ta, tb, tc), max3f(td, te, dm[15]));

        // lane arg (lowest global idx among ties) via min3 tree
        unsigned u[16];
#pragma unroll
        for (int j = 0; j < 16; ++j)
            u[j] = (dm[j] == mv) ? (unsigned)(th + j * 256) : 0xFFFFFFFFu;
        const unsigned ua = min3u(u[0], u[1], u[2]);
        const unsigned ub = min3u(u[3], u[4], u[5]);
        const unsigned uc = min3u(u[6], u[7], u[8]);
        const unsigned ud = min3u(u[9], u[10], u[11]);
        const unsigned ue = min3u(u[12], u[13], u[14]);
        const unsigned uf = min3u(ua, ub, uc);
        const unsigned ug = min3u(ud, ue, u[15]);
        const unsigned best = uf < ug ? uf : ug;

        // wave max: 4x DPP row_ror f32-max, readlane across rows
        float r = mv;
        { const float o = __int_as_float(DPP_ROR_I(__float_as_int(r), 1)); r = fmaxf(r, o); }
        { const float o = __int_as_float(DPP_ROR_I(__float_as_int(r), 2)); r = fmaxf(r, o); }
        { const float o = __int_as_float(DPP_ROR_I(__float_as_int(r), 4)); r = fmaxf(r, o); }
        { const float o = __int_as_float(DPP_ROR_I(__float_as_int(r), 8)); r = fmaxf(r, o); }
        const float q0 = __int_as_float(__builtin_amdgcn_readlane(__float_as_int(r), 0));
        const float q1 = __int_as_float(__builtin_amdgcn_readlane(__float_as_int(r), 16));
        const float q2 = __int_as_float(__builtin_amdgcn_readlane(__float_as_int(r), 32));
        const float q3 = __int_as_float(__builtin_amdgcn_readlane(__float_as_int(r), 48));
        const float wm = fmaxf(fmaxf(q0, q1), fmaxf(q2, q3));

        // wave arg: candidates where lane max == wave max, min-u32 all-reduce
        unsigned c = (mv == wm) ? best : 0xFFFFFFFFu;
        { const unsigned o = (unsigned)DPP_ROR_I(c, 1); c = o < c ? o : c; }
        { const unsigned o = (unsigned)DPP_ROR_I(c, 2); c = o < c ? o : c; }
        { const unsigned o = (unsigned)DPP_ROR_I(c, 4); c = o < c ? o : c; }
        { const unsigned o = (unsigned)DPP_ROR_I(c, 8); c = o < c ? o : c; }
        const unsigned g0 = (unsigned)__builtin_amdgcn_readlane((int)c, 0);
        const unsigned g1 = (unsigned)__builtin_amdgcn_readlane((int)c, 16);
        const unsigned g2 = (unsigned)__builtin_amdgcn_readlane((int)c, 32);
        const unsigned g3 = (unsigned)__builtin_amdgcn_readlane((int)c, 48);
        const unsigned ga = g0 < g1 ? g0 : g1;
        const unsigned gb = g2 < g3 ? g2 : g3;
        const unsigned wgi = ga < gb ? ga : gb;

        // cross-wave merge within the half (one shared barrier per iter)
        if (lane == 0) { wk[half][s & 1][wv4][0] = __float_as_uint(wm); wk[half][s & 1][wv4][1] = ~wgi; }
        __syncthreads();
        const unsigned long long k0 = ((unsigned long long)wk[half][s & 1][0][0] << 32) | wk[half][s & 1][0][1];
        const unsigned long long k1 = ((unsigned long long)wk[half][s & 1][1][0] << 32) | wk[half][s & 1][1][1];
        const unsigned long long k2 = ((unsigned long long)wk[half][s & 1][2][0] << 32) | wk[half][s & 1][2][1];
        const unsigned long long k3 = ((unsigned long long)wk[half][s & 1][3][0] << 32) | wk[half][s & 1][3][1];
        const unsigned long long ka = k0 > k1 ? k0 : k1;
        const unsigned long long kb = k2 > k3 ? k2 : k3;
        const unsigned long long kw = ka > kb ? ka : kb;

        const int wi = (int)(~(unsigned)kw);
        const float4 cc = pts4[half][wi];
        cx = cc.x; cy = cc.y; cz = cc.z;
    }

    // flush centroid history to global, coalesced per half
    __syncthreads();
    float* ob = out_xyz + (size_t)b * NS * 3;
#pragma unroll
    for (int r2 = 0; r2 < 12; ++r2) {
        const int f = th + r2 * 256;
        const int i = f / 3;
        const int cmp = f - 3 * i;
        ob[f] = hist[half][cmp][i];
    }
}

// ---------------------------------------------------------------------------
// KNN: unchanged from R10 (verified exact, DPP argmin).
// ---------------------------------------------------------------------------
#define KNN_INF 3.0e38f

__global__ __launch_bounds__(1024) void knn_kernel(const float* __restrict__ xyz,
                                                   const float* __restrict__ newxyz,
                                                   unsigned short* __restrict__ knn) {
    __shared__ float4 pts[NPTS];

    const int b = blockIdx.x >> 6;
    const int t = threadIdx.x;
    const float* xb = xyz + (size_t)b * NPTS * 3;
    for (int i = t; i < NPTS; i += 1024) {
        const float x = xb[3 * i], y = xb[3 * i + 1], z = xb[3 * i + 2];
        const float ps = __fadd_rn(__fadd_rn(__fmul_rn(x, x), __fmul_rn(y, y)), __fmul_rn(z, z));
        pts[i] = make_float4(x, y, z, ps);
    }
    __syncthreads();

    const int lane = t & 63;
    const int wv = t >> 6;
    const int s = ((blockIdx.x & 63) << 4) + wv;

    const float* q = newxyz + ((size_t)b * NS + s) * 3;
    const float qx = q[0], qy = q[1], qz = q[2];
    const float qs = __fadd_rn(__fadd_rn(__fmul_rn(qx, qx), __fmul_rn(qy, qy)), __fmul_rn(qz, qz));

    float v0 = KNN_INF, v1 = KNN_INF, v2 = KNN_INF, v3 = KNN_INF;
    int i0 = 0, i1 = 0, i2 = 0, i3 = 0;
    unsigned long long rem = 0ull;

#pragma unroll 4
    for (int j = 0; j < 64; ++j) {
        const float4 p = pts[j * 64 + lane];
        const float dot = __fmaf_rn(qz, p.z, __fmaf_rn(qy, p.y, __fmul_rn(qx, p.x)));
        const float d = __fadd_rn(__fsub_rn(qs, __fadd_rn(dot, dot)), p.w);
        const int gi = j * 64 + lane;
        const bool c0 = d < v0, c1 = d < v1, c2 = d < v2, c3 = d < v3;
        v3 = c3 ? (c2 ? v2 : d) : v3;  i3 = c3 ? (c2 ? i2 : gi) : i3;
        v2 = c2 ? (c1 ? v1 : d) : v2;  i2 = c2 ? (c1 ? i1 : gi) : i2;
        v1 = c1 ? (c0 ? v0 : d) : v1;  i1 = c1 ? (c0 ? i0 : gi) : i1;
        v0 = c0 ? d : v0;              i0 = c0 ? gi : i0;
    }

    int kidx = 0;
#pragma unroll 1
    for (int r = 0; r < NK; ++r) {
        float rv = v0;
        { const float o = __int_as_float(DPP_ROR_I(__float_as_int(rv), 1)); rv = fminf(rv, o); }
        { const float o = __int_as_float(DPP_ROR_I(__float_as_int(rv), 2)); rv = fminf(rv, o); }
        { const float o = __int_as_float(DPP_ROR_I(__float_as_int(rv), 4)); rv = fminf(rv, o); }
        { const float o = __int_as_float(DPP_ROR_I(__float_as_int(rv), 8)); rv = fminf(rv, o); }
        const float q0v = __int_as_float(__builtin_amdgcn_readlane(__float_as_int(rv), 0));
        const float q1v = __int_as_float(__builtin_amdgcn_readlane(__float_as_int(rv), 16));
        const float q2v = __int_as_float(__builtin_amdgcn_readlane(__float_as_int(rv), 32));
        const float q3v = __int_as_float(__builtin_amdgcn_readlane(__float_as_int(rv), 48));
        const float wm = fminf(fminf(q0v, q1v), fminf(q2v, q3v));

        unsigned cand = (v0 == wm) ? (unsigned)i0 : 0x7FFFFFFFu;
        { const unsigned o = (unsigned)DPP_ROR_I(cand, 1); cand = o < cand ? o : cand; }
        { const unsigned o = (unsigned)DPP_ROR_I(cand, 2); cand = o < cand ? o : cand; }
        { const unsigned o = (unsigned)DPP_ROR_I(cand, 4); cand = o < cand ? o : cand; }
        { const unsigned o = (unsigned)DPP_ROR_I(cand, 8); cand = o < cand ? o : cand; }
        const unsigned c0r = (unsigned)__builtin_amdgcn_readlane((int)cand, 0);
        const unsigned c1r = (unsigned)__builtin_amdgcn_readlane((int)cand, 16);
        const unsigned c2r = (unsigned)__builtin_amdgcn_readlane((int)cand, 32);
        const unsigned c3r = (unsigned)__builtin_amdgcn_readlane((int)cand, 48);
        const unsigned ca = c0r < c1r ? c0r : c1r;
        const unsigned cb = c2r < c3r ? c2r : c3r;
        const int bi = (int)(ca < cb ? ca : cb);

        if (lane == r) kidx = bi;
        if ((bi & 63) == lane) {
            v0 = v1; i0 = i1;
            v1 = v2; i1 = i2;
            v2 = v3; i2 = i3;
            v3 = KNN_INF;
            rem |= 1ull << (bi >> 6);
            if (v0 >= 1e37f) {
                v0 = v1 = v2 = v3 = KNN_INF;
#pragma unroll 1
                for (int j = 0; j < 64; ++j) {
                    if (!((rem >> j) & 1ull)) {
                        const float4 p = pts[j * 64 + lane];
                        const float dot = __fmaf_rn(qz, p.z, __fmaf_rn(qy, p.y, __fmul_rn(qx, p.x)));
                        const float d = __fadd_rn(__fsub_rn(qs, __fadd_rn(dot, dot)), p.w);
                        const int gi = j * 64 + lane;
                        const bool c0 = d < v0, c1 = d < v1, c2 = d < v2, c3 = d < v3;
                        v3 = c3 ? (c2 ? v2 : d) : v3;  i3 = c3 ? (c2 ? i2 : gi) : i3;
                        v2 = c2 ? (c1 ? v1 : d) : v2;  i2 = c2 ? (c1 ? i1 : gi) : i2;
                        v1 = c1 ? (c0 ? v0 : d) : v1;  i1 = c1 ? (c0 ? i0 : gi) : i1;
                        v0 = c0 ? d : v0;              i0 = c0 ? gi : i0;
                    }
                }
            }
        }
    }

    if (lane < NK) knn[(((size_t)b * NS + s) << 5) + lane] = (unsigned short)kidx;
}

// ---------------------------------------------------------------------------
// MLP via split-bf16 MFMA: unchanged from R11 (verified, absmax 0.0156).
// ---------------------------------------------------------------------------
__global__ __launch_bounds__(256) void mlp_kernel(const float* __restrict__ xyz,
                                                  const float* __restrict__ points,
                                                  const float* __restrict__ newxyz,
                                                  const unsigned short* __restrict__ knn,
                                                  const float* __restrict__ w0, const float* __restrict__ b0,
                                                  const float* __restrict__ w1, const float* __restrict__ b1,
                                                  const float* __restrict__ w2, const float* __restrict__ b2,
                                                  float* __restrict__ out) {
    __shared__ unsigned aHi[64 * 52], aLo[64 * 52];
    __shared__ unsigned bHi[64 * 36], bLo[64 * 36];
    __shared__ int sI[64];

    const int t = threadIdx.x;
    const int lane = t & 63;
    const int wv = t >> 6;
    const int g0 = blockIdx.x * 2;
    const int bb = g0 >> 10;

    if (t < 64) sI[t] = knn[((size_t)g0 + (t >> 5)) * 32 + (t & 31)];
    __syncthreads();

#pragma unroll
    for (int j = 0; j < 4; ++j) {
        const int id = j * 256 + t;
        const int row = id >> 4, qq = id & 15;
        const float4 p = *(const float4*)(points + (((size_t)bb * NPTS + sI[row]) << 6) + qq * 4);
        aHi[row * 52 + qq * 2]     = pkhi(p.x, p.y);
        aHi[row * 52 + qq * 2 + 1] = pkhi(p.z, p.w);
        aLo[row * 52 + qq * 2]     = pklo(p.x, p.y);
        aLo[row * 52 + qq * 2 + 1] = pklo(p.z, p.w);
    }
    if (t < 64) {
        const int row = t;
        const int idx = sI[row];
        const int gg = g0 + (row >> 5);
        const float* pp = xyz + ((size_t)bb * NPTS + idx) * 3;
        const float* qn = newxyz + (size_t)gg * 3;
        const float dx = pp[0] - qn[0];
        const float dy = pp[1] - qn[1];
        const float dz = pp[2] - qn[2];
        aHi[row * 52 + 32] = pkhi(dx, dy);
        aHi[row * 52 + 33] = pkhi(dz, 0.0f);
        aLo[row * 52 + 32] = pklo(dx, dy);
        aLo[row * 52 + 33] = pklo(dz, 0.0f);
    }
#pragma unroll
    for (int j = 0; j < 4; ++j) {
        const int id = j * 256 + t;
        const int row = id >> 4, c = 34 + (id & 15);
        aHi[row * 52 + c] = 0u;
        aLo[row * 52 + c] = 0u;
    }

    const int col0 = (wv << 4) + (lane & 15);
    const int kb = (lane >> 4) << 3;
    bf16x8 w0h[3], w0l[3];
#pragma unroll
    for (int kt = 0; kt < 3; ++kt) {
#pragma unroll
        for (int j = 0; j < 8; ++j) {
            const int k = kt * 32 + kb + j;
            const int worig = (k < 64) ? (k + 3) : ((k < 67) ? (k - 64) : -1);
            const float v = (worig >= 0) ? w0[worig * 64 + col0] : 0.0f;
            const unsigned short h = f2bf(v);
            w0h[kt][j] = (short)h;
            w0l[kt][j] = (short)f2bf(v - bf2f(h));
        }
    }
    const float bias0 = b0[col0];
    __syncthreads();

#pragma unroll
    for (int mt = 0; mt < 4; ++mt) {
        f32x4 acc = { bias0, bias0, bias0, bias0 };
#pragma unroll
        for (int kt = 0; kt < 3; ++kt) {
            const int base = (mt * 16 + (lane & 15)) * 52 + kt * 16 + ((lane >> 4) << 2);
            const bf16x8 ah = *(const bf16x8*)&aHi[base];
            const bf16x8 al = *(const bf16x8*)&aLo[base];
            acc = MFMA16(ah, w0h[kt], acc);
            acc = MFMA16(al, w0h[kt], acc);
            acc = MFMA16(ah, w0l[kt], acc);
        }
#pragma unroll
        for (int r = 0; r < 4; ++r) {
            const float v = fmaxf(acc[r], 0.0f);
            const int row = mt * 16 + ((lane >> 4) << 2) + r;
            const unsigned short h = f2bf(v);
            ((unsigned short*)bHi)[row * 72 + col0] = h;
            ((unsigned short*)bLo)[row * 72 + col0] = f2bf(v - bf2f(h));
        }
    }

    bf16x8 w1h[2], w1l[2];
#pragma unroll
    for (int kt = 0; kt < 2; ++kt) {
#pragma unroll
        for (int j = 0; j < 8; ++j) {
            const int k = kt * 32 + kb + j;
            const float v = w1[k * 64 + col0];
            const unsigned short h = f2bf(v);
            w1h[kt][j] = (short)h;
            w1l[kt][j] = (short)f2bf(v - bf2f(h));
        }
    }
    const float bias1 = b1[col0];
    __syncthreads();

#pragma unroll
    for (int mt = 0; mt < 4; ++mt) {
        f32x4 acc = { bias1, bias1, bias1, bias1 };
#pragma unroll
        for (int kt = 0; kt < 2; ++kt) {
            const int base = (mt * 16 + (lane & 15)) * 36 + kt * 16 + ((lane >> 4) << 2);
            const bf16x8 ah = *(const bf16x8*)&bHi[base];
            const bf16x8 al = *(const bf16x8*)&bLo[base];
            acc = MFMA16(ah, w1h[kt], acc);
            acc = MFMA16(al, w1h[kt], acc);
            acc = MFMA16(ah, w1l[kt], acc);
        }
#pragma unroll
        for (int r = 0; r < 4; ++r) {
            const float v = fmaxf(acc[r], 0.0f);
            const int row = mt * 16 + ((lane >> 4) << 2) + r;
            const unsigned short h = f2bf(v);
            ((unsigned short*)aHi)[row * 72 + col0] = h;
            ((unsigned short*)aLo)[row * 72 + col0] = f2bf(v - bf2f(h));
        }
    }

    const int colB = ((wv + 4) << 4) + (lane & 15);
    bf16x8 w2ha[2], w2la[2], w2hb[2], w2lb[2];
#pragma unroll
    for (int kt = 0; kt < 2; ++kt) {
#pragma unroll
        for (int j = 0; j < 8; ++j) {
            const int k = kt * 32 + kb + j;
            float v = w2[k * 128 + col0];
            unsigned short h = f2bf(v);
            w2ha[kt][j] = (short)h;
            w2la[kt][j] = (short)f2bf(v - bf2f(h));
            v = w2[k * 128 + colB];
            h = f2bf(v);
            w2hb[kt][j] = (short)h;
            w2lb[kt][j] = (short)f2bf(v - bf2f(h));
        }
    }
    const float bias2a = b2[col0];
    const float bias2b = b2[colB];
    __syncthreads();

#pragma unroll
    for (int gj = 0; gj < 2; ++gj) {
        f32x4 aA[2], aB[2];
#pragma unroll
        for (int hh = 0; hh < 2; ++hh) {
            const int mt = gj * 2 + hh;
            f32x4 accA = { bias2a, bias2a, bias2a, bias2a };
            f32x4 accB = { bias2b, bias2b, bias2b, bias2b };
#pragma unroll
            for (int kt = 0; kt < 2; ++kt) {
                const int base = (mt * 16 + (lane & 15)) * 36 + kt * 16 + ((lane >> 4) << 2);
                const bf16x8 ah = *(const bf16x8*)&aHi[base];
                const bf16x8 al = *(const bf16x8*)&aLo[base];
                accA = MFMA16(ah, w2ha[kt], accA);
                accA = MFMA16(al, w2ha[kt], accA);
                accA = MFMA16(ah, w2la[kt], accA);
                accB = MFMA16(ah, w2hb[kt], accB);
                accB = MFMA16(al, w2hb[kt], accB);
                accB = MFMA16(ah, w2lb[kt], accB);
            }
            aA[hh] = accA;
            aB[hh] = accB;
        }
        float mA = max3f(max3f(aA[0][0], aA[0][1], aA[0][2]),
                         max3f(aA[0][3], aA[1][0], aA[1][1]),
                         fmaxf(aA[1][2], aA[1][3]));
        float mB = max3f(max3f(aB[0][0], aB[0][1], aB[0][2]),
                         max3f(aB[0][3], aB[1][0], aB[1][1]),
                         fmaxf(aB[1][2], aB[1][3]));
        mA = fmaxf(mA, __shfl_xor(mA, 16));
        mA = fmaxf(mA, __shfl_xor(mA, 32));
        mB = fmaxf(mB, __shfl_xor(mB, 16));
        mB = fmaxf(mB, __shfl_xor(mB, 32));
        mA = fmaxf(mA, 0.0f);
        mB = fmaxf(mB, 0.0f);
        float* op = out + (size_t)(g0 + gj) * 128;
        if (lane < 16) {
            op[(wv << 4) + lane] = mA;
            op[((wv + 4) << 4) + lane] = mB;
        }
    }
}

extern "C" void kernel_launch(void* const* d_in, const int* in_sizes, int n_in,
                              void* d_out, int out_size, void* d_ws, size_t ws_size,
                              hipStream_t stream) {
    const float* xyz    = (const float*)d_in[0];
    const float* points = (const float*)d_in[1];
    const float* w0 = (const float*)d_in[2];
    const float* b0 = (const float*)d_in[3];
    const float* w1 = (const float*)d_in[4];
    const float* b1 = (const float*)d_in[5];
    const float* w2 = (const float*)d_in[6];
    const float* b2 = (const float*)d_in[7];

    float* out = (float*)d_out;
    float* newxyz = out;                          // (B, S, 3)
    float* newpts = out + (size_t)NB * NS * 3;    // (B, S, 128)
    unsigned short* knn = (unsigned short*)d_ws;  // (B, S, K) u16, 1 MB

    fps_kernel<<<NB / 2, 512, 0, stream>>>(xyz, newxyz);
    knn_kernel<<<NB * (NS / 16), 1024, 0, stream>>>(xyz, newxyz, knn);
    mlp_kernel<<<(NB * NS) / 2, 256, 0, stream>>>(xyz, points, newxyz, knn,
                                                  w0, b0, w1, b1, w2, b2, newpts);
}

// Round 13
// 739.898 us; speedup vs baseline: 1.4921x; 1.4921x over previous
//
#include <hip/hip_runtime.h>

#define NB 16
#define NPTS 4096
#define NC 64
#define NS 1024
#define NK 32

typedef float v2f __attribute__((ext_vector_type(2)));
typedef short bf16x8 __attribute__((ext_vector_type(8)));
typedef float f32x4 __attribute__((ext_vector_type(4)));

#define DPP_ROR_I(x, N) __builtin_amdgcn_update_dpp(0, (int)(x), 0x120 + (N), 0xf, 0xf, false)
#define MFMA16(a, b, c) __builtin_amdgcn_mfma_f32_16x16x32_bf16((a), (b), (c), 0, 0, 0)

static __device__ __forceinline__ float max3f(float a, float b, float c) {
    return fmaxf(fmaxf(a, b), c);
}
static __device__ __forceinline__ unsigned min3u(unsigned a, unsigned b, unsigned c) {
    const unsigned m = a < b ? a : b;
    return m < c ? m : c;
}
static __device__ __forceinline__ unsigned short f2bf(float f) {
    const unsigned u = __float_as_uint(f);
    const unsigned r = 0x7FFFu + ((u >> 16) & 1u);
    return (unsigned short)((u + r) >> 16);
}
static __device__ __forceinline__ float bf2f(unsigned short h) {
    return __uint_as_float(((unsigned)h) << 16);
}
static __device__ __forceinline__ unsigned pkhi(float a, float b) {
    return (unsigned)f2bf(a) | ((unsigned)f2bf(b) << 16);
}
static __device__ __forceinline__ unsigned pklo(float a, float b) {
    const float la = a - bf2f(f2bf(a));
    const float lb = b - bf2f(f2bf(b));
    return (unsigned)f2bf(la) | ((unsigned)f2bf(lb) << 16);
}

#define KNN_INF 3.0e38f

// LDS layout (union):
//   [0, 65536)          float4 pts[4096]        (fps: w=0; consumer: w=psq)
//   fps:      [65536, 77824) hist[3][1024];  [77824, 77888) wk[2][4][2]
//   consumer: [65536,+13312) aHi; +13312 aLo; +9216 bHi; +9216 bLo;
//             +512 sIc[128]; +48 nqc[12]
#define SMEM_BYTES 111168

__global__ __launch_bounds__(256) void fused_kernel(
        const float* __restrict__ xyz, const float* __restrict__ points,
        const float* __restrict__ w0, const float* __restrict__ b0,
        const float* __restrict__ w1, const float* __restrict__ b1,
        const float* __restrict__ w2, const float* __restrict__ b2,
        float* __restrict__ out, unsigned* __restrict__ progress) {
    __shared__ __align__(16) char smem[SMEM_BYTES];
    float4* pts = (float4*)smem;

    const int t = threadIdx.x;
    const int lane = t & 63;
    const int wv = t >> 6;
    float* newxyz = out;                         // (B,S,3)
    float* outpts = out + (size_t)NB * NS * 3;   // (B,S,128)

    if (blockIdx.x < NB) {
        // ================= FPS producer (R10-verified core) =================
        float* hist = (float*)(smem + 65536);          // [3][1024]
        unsigned* wk = (unsigned*)(smem + 65536 + 12288); // [2][4][2]
        const int b = blockIdx.x;

        const float* xb = xyz + (size_t)b * NPTS * 3;
        for (int i = t; i < NPTS; i += 256) {
            pts[i] = make_float4(xb[3 * i], xb[3 * i + 1], xb[3 * i + 2], 0.0f);
        }
        __syncthreads();

        v2f PX[8], PY[8], PZ[8];
        float dm[16];
#pragma unroll
        for (int k = 0; k < 8; ++k) {
            const float4 p0 = pts[t + (2 * k) * 256];
            const float4 p1 = pts[t + (2 * k + 1) * 256];
            PX[k].x = p0.x; PX[k].y = p1.x;
            PY[k].x = p0.y; PY[k].y = p1.y;
            PZ[k].x = p0.z; PZ[k].y = p1.z;
            dm[2 * k] = 1e10f; dm[2 * k + 1] = 1e10f;
        }

        const float4 c0 = pts[0];
        float cx = c0.x, cy = c0.y, cz = c0.z;
        float* ob = newxyz + (size_t)b * NS * 3;

        for (int s = 0; s < NS; ++s) {
            if (t == 0) { hist[s] = cx; hist[1024 + s] = cy; hist[2048 + s] = cz; }

            const v2f cX = { cx, cx };
            const v2f cY = { cy, cy };
            const v2f cZ = { cz, cz };
#pragma unroll
            for (int k = 0; k < 8; ++k) {
                const v2f dX = PX[k] - cX;
                const v2f dY = PY[k] - cY;
                const v2f dZ = PZ[k] - cZ;
                const v2f t1 = dX * dX;
                const v2f t2 = dY * dY;
                const v2f t3 = dZ * dZ;
                const v2f ss = (t1 + t2) + t3;
                dm[2 * k] = fminf(dm[2 * k], ss.x);
                dm[2 * k + 1] = fminf(dm[2 * k + 1], ss.y);
            }

            const float ta = max3f(dm[0], dm[1], dm[2]);
            const float tb = max3f(dm[3], dm[4], dm[5]);
            const float tc = max3f(dm[6], dm[7], dm[8]);
            const float td = max3f(dm[9], dm[10], dm[11]);
            const float te = max3f(dm[12], dm[13], dm[14]);
            const float mv = fmaxf(max3f(ta, tb, tc), max3f(td, te, dm[15]));

            unsigned u[16];
#pragma unroll
            for (int j = 0; j < 16; ++j)
                u[j] = (dm[j] == mv) ? (unsigned)(t + j * 256) : 0xFFFFFFFFu;
            const unsigned ua = min3u(u[0], u[1], u[2]);
            const unsigned ub = min3u(u[3], u[4], u[5]);
            const unsigned uc = min3u(u[6], u[7], u[8]);
            const unsigned ud = min3u(u[9], u[10], u[11]);
            const unsigned ue = min3u(u[12], u[13], u[14]);
            const unsigned uf = min3u(ua, ub, uc);
            const unsigned ug = min3u(ud, ue, u[15]);
            const unsigned best = uf < ug ? uf : ug;

            float r = mv;
            { const float o = __int_as_float(DPP_ROR_I(__float_as_int(r), 1)); r = fmaxf(r, o); }
            { const float o = __int_as_float(DPP_ROR_I(__float_as_int(r), 2)); r = fmaxf(r, o); }
            { const float o = __int_as_float(DPP_ROR_I(__float_as_int(r), 4)); r = fmaxf(r, o); }
            { const float o = __int_as_float(DPP_ROR_I(__float_as_int(r), 8)); r = fmaxf(r, o); }
            const float q0 = __int_as_float(__builtin_amdgcn_readlane(__float_as_int(r), 0));
            const float q1 = __int_as_float(__builtin_amdgcn_readlane(__float_as_int(r), 16));
            const float q2 = __int_as_float(__builtin_amdgcn_readlane(__float_as_int(r), 32));
            const float q3 = __int_as_float(__builtin_amdgcn_readlane(__float_as_int(r), 48));
            const float wm = fmaxf(fmaxf(q0, q1), fmaxf(q2, q3));

            unsigned c = (mv == wm) ? best : 0xFFFFFFFFu;
            { const unsigned o = (unsigned)DPP_ROR_I(c, 1); c = o < c ? o : c; }
            { const unsigned o = (unsigned)DPP_ROR_I(c, 2); c = o < c ? o : c; }
            { const unsigned o = (unsigned)DPP_ROR_I(c, 4); c = o < c ? o : c; }
            { const unsigned o = (unsigned)DPP_ROR_I(c, 8); c = o < c ? o : c; }
            const unsigned g0v = (unsigned)__builtin_amdgcn_readlane((int)c, 0);
            const unsigned g1v = (unsigned)__builtin_amdgcn_readlane((int)c, 16);
            const unsigned g2v = (unsigned)__builtin_amdgcn_readlane((int)c, 32);
            const unsigned g3v = (unsigned)__builtin_amdgcn_readlane((int)c, 48);
            const unsigned ga = g0v < g1v ? g0v : g1v;
            const unsigned gb = g2v < g3v ? g2v : g3v;
            const unsigned wgi = ga < gb ? ga : gb;

            if (lane == 0) { wk[((s & 1) * 4 + wv) * 2] = __float_as_uint(wm); wk[((s & 1) * 4 + wv) * 2 + 1] = ~wgi; }
            __syncthreads();
            const unsigned* wb = &wk[(s & 1) * 8];
            const unsigned long long k0 = ((unsigned long long)wb[0] << 32) | wb[1];
            const unsigned long long k1 = ((unsigned long long)wb[2] << 32) | wb[3];
            const unsigned long long k2 = ((unsigned long long)wb[4] << 32) | wb[5];
            const unsigned long long k3 = ((unsigned long long)wb[6] << 32) | wb[7];
            const unsigned long long ka = k0 > k1 ? k0 : k1;
            const unsigned long long kb = k2 > k3 ? k2 : k3;
            const unsigned long long kw = ka > kb ? ka : kb;

            // chunked publish: every 16 iters, wave0 flushes 16 centroids
            if ((s & 15) == 15) {
                if (t < 64) {
                    if (t < 48) {
                        const int f = (s & ~15) * 3 + t;
                        ob[f] = hist[(f % 3) * 1024 + f / 3];
                    }
                    __threadfence();
                }
                if (t == 0)
                    __hip_atomic_fetch_add(&progress[b], 16u, __ATOMIC_RELEASE, __HIP_MEMORY_SCOPE_AGENT);
            }

            const int wi = (int)(~(unsigned)kw);
            const float4 cc = pts[wi];
            cx = cc.x; cy = cc.y; cz = cc.z;
        }
    } else {
        // ================= KNN + MLP consumer =================
        unsigned* aHi = (unsigned*)(smem + 65536);
        unsigned* aLo = aHi + 64 * 52;
        unsigned* bHi = aLo + 64 * 52;
        unsigned* bLo = bHi + 64 * 36;
        int* sIc = (int*)(bLo + 64 * 36);      // [4][32]
        float* nqc = (float*)(sIc + 128);      // [4][3]

        const int w = blockIdx.x - NB;
        const int batch = w & 15;
        const int widx = w >> 4;               // 0..14

        // stage xyz + psq once per block (batch fixed)
        const float* xb = xyz + (size_t)batch * NPTS * 3;
        for (int i = t; i < NPTS; i += 256) {
            const float x = xb[3 * i], y = xb[3 * i + 1], z = xb[3 * i + 2];
            const float ps = __fadd_rn(__fadd_rn(__fmul_rn(x, x), __fmul_rn(y, y)), __fmul_rn(z, z));
            pts[i] = make_float4(x, y, z, ps);
        }
        __syncthreads();

        const int col0 = (wv << 4) + (lane & 15);
        const int kb = (lane >> 4) << 3;

        for (int chunk = widx; chunk < 256; chunk += 15) {
            const int s0 = chunk * 4;
            // wait for centroids s0..s0+3
            if (t == 0) {
                while (__hip_atomic_load(&progress[batch], __ATOMIC_ACQUIRE, __HIP_MEMORY_SCOPE_AGENT)
                       < (unsigned)(s0 + 4))
                    __builtin_amdgcn_s_sleep(16);
            }
            __syncthreads();

            // ---- KNN: one wave per query (R10-verified algorithm)
            {
                const int s = s0 + wv;
                const unsigned* qp = (const unsigned*)(newxyz + ((size_t)batch * NS + s) * 3);
                const float qx = __uint_as_float(__hip_atomic_load(qp + 0, __ATOMIC_RELAXED, __HIP_MEMORY_SCOPE_AGENT));
                const float qy = __uint_as_float(__hip_atomic_load(qp + 1, __ATOMIC_RELAXED, __HIP_MEMORY_SCOPE_AGENT));
                const float qz = __uint_as_float(__hip_atomic_load(qp + 2, __ATOMIC_RELAXED, __HIP_MEMORY_SCOPE_AGENT));
                const float qs = __fadd_rn(__fadd_rn(__fmul_rn(qx, qx), __fmul_rn(qy, qy)), __fmul_rn(qz, qz));

                float v0 = KNN_INF, v1 = KNN_INF, v2 = KNN_INF, v3 = KNN_INF;
                int i0 = 0, i1 = 0, i2 = 0, i3 = 0;
                unsigned long long rem = 0ull;

#pragma unroll 4
                for (int j = 0; j < 64; ++j) {
                    const float4 p = pts[j * 64 + lane];
                    const float dot = __fmaf_rn(qz, p.z, __fmaf_rn(qy, p.y, __fmul_rn(qx, p.x)));
                    const float d = __fadd_rn(__fsub_rn(qs, __fadd_rn(dot, dot)), p.w);
                    const int gi = j * 64 + lane;
                    const bool c0 = d < v0, c1 = d < v1, c2 = d < v2, c3 = d < v3;
                    v3 = c3 ? (c2 ? v2 : d) : v3;  i3 = c3 ? (c2 ? i2 : gi) : i3;
                    v2 = c2 ? (c1 ? v1 : d) : v2;  i2 = c2 ? (c1 ? i1 : gi) : i2;
                    v1 = c1 ? (c0 ? v0 : d) : v1;  i1 = c1 ? (c0 ? i0 : gi) : i1;
                    v0 = c0 ? d : v0;              i0 = c0 ? gi : i0;
                }

                int kidx = 0;
#pragma unroll 1
                for (int r = 0; r < NK; ++r) {
                    float rv = v0;
                    { const float o = __int_as_float(DPP_ROR_I(__float_as_int(rv), 1)); rv = fminf(rv, o); }
                    { const float o = __int_as_float(DPP_ROR_I(__float_as_int(rv), 2)); rv = fminf(rv, o); }
                    { const float o = __int_as_float(DPP_ROR_I(__float_as_int(rv), 4)); rv = fminf(rv, o); }
                    { const float o = __int_as_float(DPP_ROR_I(__float_as_int(rv), 8)); rv = fminf(rv, o); }
                    const float q0v = __int_as_float(__builtin_amdgcn_readlane(__float_as_int(rv), 0));
                    const float q1v = __int_as_float(__builtin_amdgcn_readlane(__float_as_int(rv), 16));
                    const float q2v = __int_as_float(__builtin_amdgcn_readlane(__float_as_int(rv), 32));
                    const float q3v = __int_as_float(__builtin_amdgcn_readlane(__float_as_int(rv), 48));
                    const float wm = fminf(fminf(q0v, q1v), fminf(q2v, q3v));

                    unsigned cand = (v0 == wm) ? (unsigned)i0 : 0x7FFFFFFFu;
                    { const unsigned o = (unsigned)DPP_ROR_I(cand, 1); cand = o < cand ? o : cand; }
                    { const unsigned o = (unsigned)DPP_ROR_I(cand, 2); cand = o < cand ? o : cand; }
                    { const unsigned o = (unsigned)DPP_ROR_I(cand, 4); cand = o < cand ? o : cand; }
                    { const unsigned o = (unsigned)DPP_ROR_I(cand, 8); cand = o < cand ? o : cand; }
                    const unsigned c0r = (unsigned)__builtin_amdgcn_readlane((int)cand, 0);
                    const unsigned c1r = (unsigned)__builtin_amdgcn_readlane((int)cand, 16);
                    const unsigned c2r = (unsigned)__builtin_amdgcn_readlane((int)cand, 32);
                    const unsigned c3r = (unsigned)__builtin_amdgcn_readlane((int)cand, 48);
                    const unsigned ca = c0r < c1r ? c0r : c1r;
                    const unsigned cb = c2r < c3r ? c2r : c3r;
                    const int bi = (int)(ca < cb ? ca : cb);

                    if (lane == r) kidx = bi;
                    if ((bi & 63) == lane) {
                        v0 = v1; i0 = i1;
                        v1 = v2; i1 = i2;
                        v2 = v3; i2 = i3;
                        v3 = KNN_INF;
                        rem |= 1ull << (bi >> 6);
                        if (v0 >= 1e37f) {
                            v0 = v1 = v2 = v3 = KNN_INF;
#pragma unroll 1
                            for (int j = 0; j < 64; ++j) {
                                if (!((rem >> j) & 1ull)) {
                                    const float4 p = pts[j * 64 + lane];
                                    const float dot = __fmaf_rn(qz, p.z, __fmaf_rn(qy, p.y, __fmul_rn(qx, p.x)));
                                    const float d = __fadd_rn(__fsub_rn(qs, __fadd_rn(dot, dot)), p.w);
                                    const int gi = j * 64 + lane;
                                    const bool c0 = d < v0, c1 = d < v1, c2 = d < v2, c3 = d < v3;
                                    v3 = c3 ? (c2 ? v2 : d) : v3;  i3 = c3 ? (c2 ? i2 : gi) : i3;
                                    v2 = c2 ? (c1 ? v1 : d) : v2;  i2 = c2 ? (c1 ? i1 : gi) : i2;
                                    v1 = c1 ? (c0 ? v0 : d) : v1;  i1 = c1 ? (c0 ? i0 : gi) : i1;
                                    v0 = c0 ? d : v0;              i0 = c0 ? gi : i0;
                                }
                            }
                        }
                    }
                }

                if (lane < NK) sIc[wv * 32 + lane] = kidx;
                if (lane == 0) { nqc[wv * 3] = qx; nqc[wv * 3 + 1] = qy; nqc[wv * 3 + 2] = qz; }
            }

            // ---- MLP: two 2-group units (R11-verified structure)
#pragma unroll 1
            for (int uu = 0; uu < 2; ++uu) {
                __syncthreads();   // protect aHi reuse (knn done / prior unit done)

                // gather points -> hi/lo bf16 (rows = this unit's 64 neighbors)
#pragma unroll
                for (int j = 0; j < 4; ++j) {
                    const int id = j * 256 + t;
                    const int row = id >> 4, qq = id & 15;
                    const int idx = sIc[uu * 64 + row];
                    const float4 p = *(const float4*)(points + (((size_t)batch * NPTS + idx) << 6) + qq * 4);
                    aHi[row * 52 + qq * 2]     = pkhi(p.x, p.y);
                    aHi[row * 52 + qq * 2 + 1] = pkhi(p.z, p.w);
                    aLo[row * 52 + qq * 2]     = pklo(p.x, p.y);
                    aLo[row * 52 + qq * 2 + 1] = pklo(p.z, p.w);
                }
                if (t < 64) {
                    const int row = t;
                    const int idx = sIc[uu * 64 + row];
                    const int lq = 2 * uu + (row >> 5);
                    const float* pp = xyz + ((size_t)batch * NPTS + idx) * 3;
                    const float dx = pp[0] - nqc[lq * 3];
                    const float dy = pp[1] - nqc[lq * 3 + 1];
                    const float dz = pp[2] - nqc[lq * 3 + 2];
                    aHi[row * 52 + 32] = pkhi(dx, dy);
                    aHi[row * 52 + 33] = pkhi(dz, 0.0f);
                    aLo[row * 52 + 32] = pklo(dx, dy);
                    aLo[row * 52 + 33] = pklo(dz, 0.0f);
                }
#pragma unroll
                for (int j = 0; j < 4; ++j) {
                    const int id = j * 256 + t;
                    const int row = id >> 4, c = 34 + (id & 15);
                    aHi[row * 52 + c] = 0u;
                    aLo[row * 52 + c] = 0u;
                }

                bf16x8 w0h[3], w0l[3];
#pragma unroll
                for (int kt = 0; kt < 3; ++kt) {
#pragma unroll
                    for (int j = 0; j < 8; ++j) {
                        const int k = kt * 32 + kb + j;
                        const int worig = (k < 64) ? (k + 3) : ((k < 67) ? (k - 64) : -1);
                        const float v = (worig >= 0) ? w0[worig * 64 + col0] : 0.0f;
                        const unsigned short h = f2bf(v);
                        w0h[kt][j] = (short)h;
                        w0l[kt][j] = (short)f2bf(v - bf2f(h));
                    }
                }
                const float bias0 = b0[col0];
                __syncthreads();

#pragma unroll
                for (int mt = 0; mt < 4; ++mt) {
                    f32x4 acc = { bias0, bias0, bias0, bias0 };
#pragma unroll
                    for (int kt = 0; kt < 3; ++kt) {
                        const int base = (mt * 16 + (lane & 15)) * 52 + kt * 16 + ((lane >> 4) << 2);
                        const bf16x8 ah = *(const bf16x8*)&aHi[base];
                        const bf16x8 al = *(const bf16x8*)&aLo[base];
                        acc = MFMA16(ah, w0h[kt], acc);
                        acc = MFMA16(al, w0h[kt], acc);
                        acc = MFMA16(ah, w0l[kt], acc);
                    }
#pragma unroll
                    for (int r = 0; r < 4; ++r) {
                        const float v = fmaxf(acc[r], 0.0f);
                        const int row = mt * 16 + ((lane >> 4) << 2) + r;
                        const unsigned short h = f2bf(v);
                        ((unsigned short*)bHi)[row * 72 + col0] = h;
                        ((unsigned short*)bLo)[row * 72 + col0] = f2bf(v - bf2f(h));
                    }
                }

                bf16x8 w1h[2], w1l[2];
#pragma unroll
                for (int kt = 0; kt < 2; ++kt) {
#pragma unroll
                    for (int j = 0; j < 8; ++j) {
                        const int k = kt * 32 + kb + j;
                        const float v = w1[k * 64 + col0];
                        const unsigned short h = f2bf(v);
                        w1h[kt][j] = (short)h;
                        w1l[kt][j] = (short)f2bf(v - bf2f(h));
                    }
                }
                const float bias1 = b1[col0];
                __syncthreads();

#pragma unroll
                for (int mt = 0; mt < 4; ++mt) {
                    f32x4 acc = { bias1, bias1, bias1, bias1 };
#pragma unroll
                    for (int kt = 0; kt < 2; ++kt) {
                        const int base = (mt * 16 + (lane & 15)) * 36 + kt * 16 + ((lane >> 4) << 2);
                        const bf16x8 ah = *(const bf16x8*)&bHi[base];
                        const bf16x8 al = *(const bf16x8*)&bLo[base];
                        acc = MFMA16(ah, w1h[kt], acc);
                        acc = MFMA16(al, w1h[kt], acc);
                        acc = MFMA16(ah, w1l[kt], acc);
                    }
#pragma unroll
                    for (int r = 0; r < 4; ++r) {
                        const float v = fmaxf(acc[r], 0.0f);
                        const int row = mt * 16 + ((lane >> 4) << 2) + r;
                        const unsigned short h = f2bf(v);
                        ((unsigned short*)aHi)[row * 72 + col0] = h;
                        ((unsigned short*)aLo)[row * 72 + col0] = f2bf(v - bf2f(h));
                    }
                }

                const int colB = ((wv + 4) << 4) + (lane & 15);
                bf16x8 w2ha[2], w2la[2], w2hb[2], w2lb[2];
#pragma unroll
                for (int kt = 0; kt < 2; ++kt) {
#pragma unroll
                    for (int j = 0; j < 8; ++j) {
                        const int k = kt * 32 + kb + j;
                        float v = w2[k * 128 + col0];
                        unsigned short h = f2bf(v);
                        w2ha[kt][j] = (short)h;
                        w2la[kt][j] = (short)f2bf(v - bf2f(h));
                        v = w2[k * 128 + colB];
                        h = f2bf(v);
                        w2hb[kt][j] = (short)h;
                        w2lb[kt][j] = (short)f2bf(v - bf2f(h));
                    }
                }
                const float bias2a = b2[col0];
                const float bias2b = b2[colB];
                __syncthreads();

#pragma unroll
                for (int gj = 0; gj < 2; ++gj) {
                    f32x4 aA[2], aB[2];
#pragma unroll
                    for (int hh = 0; hh < 2; ++hh) {
                        const int mt = gj * 2 + hh;
                        f32x4 accA = { bias2a, bias2a, bias2a, bias2a };
                        f32x4 accB = { bias2b, bias2b, bias2b, bias2b };
#pragma unroll
                        for (int kt = 0; kt < 2; ++kt) {
                            const int base = (mt * 16 + (lane & 15)) * 36 + kt * 16 + ((lane >> 4) << 2);
                            const bf16x8 ah = *(const bf16x8*)&aHi[base];
                            const bf16x8 al = *(const bf16x8*)&aLo[base];
                            accA = MFMA16(ah, w2ha[kt], accA);
                            accA = MFMA16(al, w2ha[kt], accA);
                            accA = MFMA16(ah, w2la[kt], accA);
                            accB = MFMA16(ah, w2hb[kt], accB);
                            accB = MFMA16(al, w2hb[kt], accB);
                            accB = MFMA16(ah, w2lb[kt], accB);
                        }
                        aA[hh] = accA;
                        aB[hh] = accB;
                    }
                    float mA = max3f(max3f(aA[0][0], aA[0][1], aA[0][2]),
                                     max3f(aA[0][3], aA[1][0], aA[1][1]),
                                     fmaxf(aA[1][2], aA[1][3]));
                    float mB = max3f(max3f(aB[0][0], aB[0][1], aB[0][2]),
                                     max3f(aB[0][3], aB[1][0], aB[1][1]),
                                     fmaxf(aB[1][2], aB[1][3]));
                    mA = fmaxf(mA, __shfl_xor(mA, 16));
                    mA = fmaxf(mA, __shfl_xor(mA, 32));
                    mB = fmaxf(mB, __shfl_xor(mB, 16));
                    mB = fmaxf(mB, __shfl_xor(mB, 32));
                    mA = fmaxf(mA, 0.0f);
                    mB = fmaxf(mB, 0.0f);
                    float* op = outpts + (size_t)((size_t)batch * NS + s0 + 2 * uu + gj) * 128;
                    if (lane < 16) {
                        op[(wv << 4) + lane] = mA;
                        op[((wv + 4) << 4) + lane] = mB;
                    }
                }
            }
        }
    }
}

extern "C" void kernel_launch(void* const* d_in, const int* in_sizes, int n_in,
                              void* d_out, int out_size, void* d_ws, size_t ws_size,
                              hipStream_t stream) {
    const float* xyz    = (const float*)d_in[0];
    const float* points = (const float*)d_in[1];
    const float* w0 = (const float*)d_in[2];
    const float* b0 = (const float*)d_in[3];
    const float* w1 = (const float*)d_in[4];
    const float* b1 = (const float*)d_in[5];
    const float* w2 = (const float*)d_in[6];
    const float* b2 = (const float*)d_in[7];

    unsigned* progress = (unsigned*)d_ws;  // 16 u32 counters
    hipMemsetAsync(progress, 0, 64, stream);

    fused_kernel<<<256, 256, 0, stream>>>(xyz, points, w0, b0, w1, b1, w2, b2,
                                          (float*)d_out, progress);
}

// Round 14
// 735.545 us; speedup vs baseline: 1.5009x; 1.0059x over previous
//
#include <hip/hip_runtime.h>

#define NB 16
#define NPTS 4096
#define NC 64
#define NS 1024
#define NK 32

typedef float v2f __attribute__((ext_vector_type(2)));
typedef short bf16x8 __attribute__((ext_vector_type(8)));
typedef float f32x4 __attribute__((ext_vector_type(4)));

#define DPP_ROR_I(x, N) __builtin_amdgcn_update_dpp(0, (int)(x), 0x120 + (N), 0xf, 0xf, false)
#define MFMA16(a, b, c) __builtin_amdgcn_mfma_f32_16x16x32_bf16((a), (b), (c), 0, 0, 0)

static __device__ __forceinline__ float max3f(float a, float b, float c) {
    return fmaxf(fmaxf(a, b), c);
}
static __device__ __forceinline__ unsigned min3u(unsigned a, unsigned b, unsigned c) {
    const unsigned m = a < b ? a : b;
    return m < c ? m : c;
}
static __device__ __forceinline__ unsigned short f2bf(float f) {
    const unsigned u = __float_as_uint(f);
    const unsigned r = 0x7FFFu + ((u >> 16) & 1u);
    return (unsigned short)((u + r) >> 16);
}
static __device__ __forceinline__ float bf2f(unsigned short h) {
    return __uint_as_float(((unsigned)h) << 16);
}
static __device__ __forceinline__ unsigned pkhi(float a, float b) {
    return (unsigned)f2bf(a) | ((unsigned)f2bf(b) << 16);
}
static __device__ __forceinline__ unsigned pklo(float a, float b) {
    const float la = a - bf2f(f2bf(a));
    const float lb = b - bf2f(f2bf(b));
    return (unsigned)f2bf(la) | ((unsigned)f2bf(lb) << 16);
}

#define KNN_INF 3.0e38f
#define SMEM_BYTES 111168

__global__ __launch_bounds__(256) void fused_kernel(
        const float* __restrict__ xyz, const float* __restrict__ points,
        const float* __restrict__ w0, const float* __restrict__ b0,
        const float* __restrict__ w1, const float* __restrict__ b1,
        const float* __restrict__ w2, const float* __restrict__ b2,
        float* __restrict__ out, unsigned* __restrict__ progress) {
    __shared__ __align__(16) char smem[SMEM_BYTES];
    float4* pts = (float4*)smem;

    const int t = threadIdx.x;
    const int lane = t & 63;
    const int wv = t >> 6;
    float* newxyz = out;                         // (B,S,3)
    float* outpts = out + (size_t)NB * NS * 3;   // (B,S,128)

    if (blockIdx.x < NB) {
        // ================= FPS producer (R10-verified core) =================
        float* hist = (float*)(smem + 65536);             // [3][1024]
        unsigned* wk = (unsigned*)(smem + 65536 + 12288); // [2][4][2]
        const int b = blockIdx.x;

        const float* xb = xyz + (size_t)b * NPTS * 3;
        for (int i = t; i < NPTS; i += 256) {
            pts[i] = make_float4(xb[3 * i], xb[3 * i + 1], xb[3 * i + 2], 0.0f);
        }
        __syncthreads();

        v2f PX[8], PY[8], PZ[8];
        float dm[16];
#pragma unroll
        for (int k = 0; k < 8; ++k) {
            const float4 p0 = pts[t + (2 * k) * 256];
            const float4 p1 = pts[t + (2 * k + 1) * 256];
            PX[k].x = p0.x; PX[k].y = p1.x;
            PY[k].x = p0.y; PY[k].y = p1.y;
            PZ[k].x = p0.z; PZ[k].y = p1.z;
            dm[2 * k] = 1e10f; dm[2 * k + 1] = 1e10f;
        }

        const float4 c0 = pts[0];
        float cx = c0.x, cy = c0.y, cz = c0.z;
        unsigned* obu = (unsigned*)(newxyz + (size_t)b * NS * 3);

        for (int s = 0; s < NS; ++s) {
            // deferred ordering point for the flush issued 16 iters ago:
            // stores have long retired -> vmcnt(0) is ~free; relaxed agent add.
            if ((s & 15) == 0 && s > 0) {
                if (t == 0) {
                    asm volatile("s_waitcnt vmcnt(0)" ::: "memory");
                    __hip_atomic_fetch_add(&progress[b], 16u, __ATOMIC_RELAXED, __HIP_MEMORY_SCOPE_AGENT);
                }
            }
            if (t == 0) { hist[s] = cx; hist[1024 + s] = cy; hist[2048 + s] = cz; }

            const v2f cX = { cx, cx };
            const v2f cY = { cy, cy };
            const v2f cZ = { cz, cz };
#pragma unroll
            for (int k = 0; k < 8; ++k) {
                const v2f dX = PX[k] - cX;
                const v2f dY = PY[k] - cY;
                const v2f dZ = PZ[k] - cZ;
                const v2f t1 = dX * dX;
                const v2f t2 = dY * dY;
                const v2f t3 = dZ * dZ;
                const v2f ss = (t1 + t2) + t3;
                dm[2 * k] = fminf(dm[2 * k], ss.x);
                dm[2 * k + 1] = fminf(dm[2 * k + 1], ss.y);
            }

            const float ta = max3f(dm[0], dm[1], dm[2]);
            const float tb = max3f(dm[3], dm[4], dm[5]);
            const float tc = max3f(dm[6], dm[7], dm[8]);
            const float td = max3f(dm[9], dm[10], dm[11]);
            const float te = max3f(dm[12], dm[13], dm[14]);
            const float mv = fmaxf(max3f(ta, tb, tc), max3f(td, te, dm[15]));

            unsigned u[16];
#pragma unroll
            for (int j = 0; j < 16; ++j)
                u[j] = (dm[j] == mv) ? (unsigned)(t + j * 256) : 0xFFFFFFFFu;
            const unsigned ua = min3u(u[0], u[1], u[2]);
            const unsigned ub = min3u(u[3], u[4], u[5]);
            const unsigned uc = min3u(u[6], u[7], u[8]);
            const unsigned ud = min3u(u[9], u[10], u[11]);
            const unsigned ue = min3u(u[12], u[13], u[14]);
            const unsigned uf = min3u(ua, ub, uc);
            const unsigned ug = min3u(ud, ue, u[15]);
            const unsigned best = uf < ug ? uf : ug;

            float r = mv;
            { const float o = __int_as_float(DPP_ROR_I(__float_as_int(r), 1)); r = fmaxf(r, o); }
            { const float o = __int_as_float(DPP_ROR_I(__float_as_int(r), 2)); r = fmaxf(r, o); }
            { const float o = __int_as_float(DPP_ROR_I(__float_as_int(r), 4)); r = fmaxf(r, o); }
            { const float o = __int_as_float(DPP_ROR_I(__float_as_int(r), 8)); r = fmaxf(r, o); }
            const float q0 = __int_as_float(__builtin_amdgcn_readlane(__float_as_int(r), 0));
            const float q1 = __int_as_float(__builtin_amdgcn_readlane(__float_as_int(r), 16));
            const float q2 = __int_as_float(__builtin_amdgcn_readlane(__float_as_int(r), 32));
            const float q3 = __int_as_float(__builtin_amdgcn_readlane(__float_as_int(r), 48));
            const float wm = fmaxf(fmaxf(q0, q1), fmaxf(q2, q3));

            unsigned c = (mv == wm) ? best : 0xFFFFFFFFu;
            { const unsigned o = (unsigned)DPP_ROR_I(c, 1); c = o < c ? o : c; }
            { const unsigned o = (unsigned)DPP_ROR_I(c, 2); c = o < c ? o : c; }
            { const unsigned o = (unsigned)DPP_ROR_I(c, 4); c = o < c ? o : c; }
            { const unsigned o = (unsigned)DPP_ROR_I(c, 8); c = o < c ? o : c; }
            const unsigned g0v = (unsigned)__builtin_amdgcn_readlane((int)c, 0);
            const unsigned g1v = (unsigned)__builtin_amdgcn_readlane((int)c, 16);
            const unsigned g2v = (unsigned)__builtin_amdgcn_readlane((int)c, 32);
            const unsigned g3v = (unsigned)__builtin_amdgcn_readlane((int)c, 48);
            const unsigned ga = g0v < g1v ? g0v : g1v;
            const unsigned gb = g2v < g3v ? g2v : g3v;
            const unsigned wgi = ga < gb ? ga : gb;

            if (lane == 0) { wk[((s & 1) * 4 + wv) * 2] = __float_as_uint(wm); wk[((s & 1) * 4 + wv) * 2 + 1] = ~wgi; }
            __syncthreads();
            const unsigned* wb = &wk[(s & 1) * 8];
            const unsigned long long k0 = ((unsigned long long)wb[0] << 32) | wb[1];
            const unsigned long long k1 = ((unsigned long long)wb[2] << 32) | wb[3];
            const unsigned long long k2 = ((unsigned long long)wb[4] << 32) | wb[5];
            const unsigned long long k3 = ((unsigned long long)wb[6] << 32) | wb[7];
            const unsigned long long ka = k0 > k1 ? k0 : k1;
            const unsigned long long kb = k2 > k3 ? k2 : k3;
            const unsigned long long kw = ka > kb ? ka : kb;

            // flush 16 centroids as write-through agent atomic stores (no fence)
            if ((s & 15) == 15 && t < 48) {
                const int f = (s & ~15) * 3 + t;
                __hip_atomic_store(obu + f, __float_as_uint(hist[(f % 3) * 1024 + f / 3]),
                                   __ATOMIC_RELAXED, __HIP_MEMORY_SCOPE_AGENT);
            }

            const int wi = (int)(~(unsigned)kw);
            const float4 cc = pts[wi];
            cx = cc.x; cy = cc.y; cz = cc.z;
        }
        // final ordering point for the last flush
        if (t == 0) {
            asm volatile("s_waitcnt vmcnt(0)" ::: "memory");
            __hip_atomic_fetch_add(&progress[b], 16u, __ATOMIC_RELAXED, __HIP_MEMORY_SCOPE_AGENT);
        }
    } else {
        // ================= KNN + MLP consumer =================
        unsigned* aHi = (unsigned*)(smem + 65536);
        unsigned* aLo = aHi + 64 * 52;
        unsigned* bHi = aLo + 64 * 52;
        unsigned* bLo = bHi + 64 * 36;
        int* sIc = (int*)(bLo + 64 * 36);      // [4][32]
        float* nqc = (float*)(sIc + 128);      // [4][3]

        const int w = blockIdx.x - NB;
        const int batch = w & 15;
        const int widx = w >> 4;               // 0..14

        const float* xb = xyz + (size_t)batch * NPTS * 3;
        for (int i = t; i < NPTS; i += 256) {
            const float x = xb[3 * i], y = xb[3 * i + 1], z = xb[3 * i + 2];
            const float ps = __fadd_rn(__fadd_rn(__fmul_rn(x, x), __fmul_rn(y, y)), __fmul_rn(z, z));
            pts[i] = make_float4(x, y, z, ps);
        }
        __syncthreads();

        const int col0 = (wv << 4) + (lane & 15);
        const int kb = (lane >> 4) << 3;

        for (int chunk = widx; chunk < 256; chunk += 15) {
            const int s0 = chunk * 4;
            // relaxed poll (no cache invalidation; loads go to coherence point)
            if (t == 0) {
                while (__hip_atomic_load(&progress[batch], __ATOMIC_RELAXED, __HIP_MEMORY_SCOPE_AGENT)
                       < (unsigned)(s0 + 4))
                    __builtin_amdgcn_s_sleep(16);
            }
            __syncthreads();

            // ---- KNN: one wave per query (R10-verified algorithm)
            {
                const int s = s0 + wv;
                const unsigned* qp = (const unsigned*)(newxyz + ((size_t)batch * NS + s) * 3);
                const float qx = __uint_as_float(__hip_atomic_load(qp + 0, __ATOMIC_RELAXED, __HIP_MEMORY_SCOPE_AGENT));
                const float qy = __uint_as_float(__hip_atomic_load(qp + 1, __ATOMIC_RELAXED, __HIP_MEMORY_SCOPE_AGENT));
                const float qz = __uint_as_float(__hip_atomic_load(qp + 2, __ATOMIC_RELAXED, __HIP_MEMORY_SCOPE_AGENT));
                const float qs = __fadd_rn(__fadd_rn(__fmul_rn(qx, qx), __fmul_rn(qy, qy)), __fmul_rn(qz, qz));

                float v0 = KNN_INF, v1 = KNN_INF, v2 = KNN_INF, v3 = KNN_INF;
                int i0 = 0, i1 = 0, i2 = 0, i3 = 0;
                unsigned long long rem = 0ull;

#pragma unroll 4
                for (int j = 0; j < 64; ++j) {
                    const float4 p = pts[j * 64 + lane];
                    const float dot = __fmaf_rn(qz, p.z, __fmaf_rn(qy, p.y, __fmul_rn(qx, p.x)));
                    const float d = __fadd_rn(__fsub_rn(qs, __fadd_rn(dot, dot)), p.w);
                    const int gi = j * 64 + lane;
                    const bool c0 = d < v0, c1 = d < v1, c2 = d < v2, c3 = d < v3;
                    v3 = c3 ? (c2 ? v2 : d) : v3;  i3 = c3 ? (c2 ? i2 : gi) : i3;
                    v2 = c2 ? (c1 ? v1 : d) : v2;  i2 = c2 ? (c1 ? i1 : gi) : i2;
                    v1 = c1 ? (c0 ? v0 : d) : v1;  i1 = c1 ? (c0 ? i0 : gi) : i1;
                    v0 = c0 ? d : v0;              i0 = c0 ? gi : i0;
                }

                int kidx = 0;
#pragma unroll 1
                for (int r = 0; r < NK; ++r) {
                    float rv = v0;
                    { const float o = __int_as_float(DPP_ROR_I(__float_as_int(rv), 1)); rv = fminf(rv, o); }
                    { const float o = __int_as_float(DPP_ROR_I(__float_as_int(rv), 2)); rv = fminf(rv, o); }
                    { const float o = __int_as_float(DPP_ROR_I(__float_as_int(rv), 4)); rv = fminf(rv, o); }
                    { const float o = __int_as_float(DPP_ROR_I(__float_as_int(rv), 8)); rv = fminf(rv, o); }
                    const float q0v = __int_as_float(__builtin_amdgcn_readlane(__float_as_int(rv), 0));
                    const float q1v = __int_as_float(__builtin_amdgcn_readlane(__float_as_int(rv), 16));
                    const float q2v = __int_as_float(__builtin_amdgcn_readlane(__float_as_int(rv), 32));
                    const float q3v = __int_as_float(__builtin_amdgcn_readlane(__float_as_int(rv), 48));
                    const float wm = fminf(fminf(q0v, q1v), fminf(q2v, q3v));

                    unsigned cand = (v0 == wm) ? (unsigned)i0 : 0x7FFFFFFFu;
                    { const unsigned o = (unsigned)DPP_ROR_I(cand, 1); cand = o < cand ? o : cand; }
                    { const unsigned o = (unsigned)DPP_ROR_I(cand, 2); cand = o < cand ? o : cand; }
                    { const unsigned o = (unsigned)DPP_ROR_I(cand, 4); cand = o < cand ? o : cand; }
                    { const unsigned o = (unsigned)DPP_ROR_I(cand, 8); cand = o < cand ? o : cand; }
                    const unsigned c0r = (unsigned)__builtin_amdgcn_readlane((int)cand, 0);
                    const unsigned c1r = (unsigned)__builtin_amdgcn_readlane((int)cand, 16);
                    const unsigned c2r = (unsigned)__builtin_amdgcn_readlane((int)cand, 32);
                    const unsigned c3r = (unsigned)__builtin_amdgcn_readlane((int)cand, 48);
                    const unsigned ca = c0r < c1r ? c0r : c1r;
                    const unsigned cb = c2r < c3r ? c2r : c3r;
                    const int bi = (int)(ca < cb ? ca : cb);

                    if (lane == r) kidx = bi;
                    if ((bi & 63) == lane) {
                        v0 = v1; i0 = i1;
                        v1 = v2; i1 = i2;
                        v2 = v3; i2 = i3;
                        v3 = KNN_INF;
                        rem |= 1ull << (bi >> 6);
                        if (v0 >= 1e37f) {
                            v0 = v1 = v2 = v3 = KNN_INF;
#pragma unroll 1
                            for (int j = 0; j < 64; ++j) {
                                if (!((rem >> j) & 1ull)) {
                                    const float4 p = pts[j * 64 + lane];
                                    const float dot = __fmaf_rn(qz, p.z, __fmaf_rn(qy, p.y, __fmul_rn(qx, p.x)));
                                    const float d = __fadd_rn(__fsub_rn(qs, __fadd_rn(dot, dot)), p.w);
                                    const int gi = j * 64 + lane;
                                    const bool c0 = d < v0, c1 = d < v1, c2 = d < v2, c3 = d < v3;
                                    v3 = c3 ? (c2 ? v2 : d) : v3;  i3 = c3 ? (c2 ? i2 : gi) : i3;
                                    v2 = c2 ? (c1 ? v1 : d) : v2;  i2 = c2 ? (c1 ? i1 : gi) : i2;
                                    v1 = c1 ? (c0 ? v0 : d) : v1;  i1 = c1 ? (c0 ? i0 : gi) : i1;
                                    v0 = c0 ? d : v0;              i0 = c0 ? gi : i0;
                                }
                            }
                        }
                    }
                }

                if (lane < NK) sIc[wv * 32 + lane] = kidx;
                if (lane == 0) { nqc[wv * 3] = qx; nqc[wv * 3 + 1] = qy; nqc[wv * 3 + 2] = qz; }
            }

            // ---- MLP: two 2-group units (R11-verified structure)
#pragma unroll 1
            for (int uu = 0; uu < 2; ++uu) {
                __syncthreads();

#pragma unroll
                for (int j = 0; j < 4; ++j) {
                    const int id = j * 256 + t;
                    const int row = id >> 4, qq = id & 15;
                    const int idx = sIc[uu * 64 + row];
                    const float4 p = *(const float4*)(points + (((size_t)batch * NPTS + idx) << 6) + qq * 4);
                    aHi[row * 52 + qq * 2]     = pkhi(p.x, p.y);
                    aHi[row * 52 + qq * 2 + 1] = pkhi(p.z, p.w);
                    aLo[row * 52 + qq * 2]     = pklo(p.x, p.y);
                    aLo[row * 52 + qq * 2 + 1] = pklo(p.z, p.w);
                }
                if (t < 64) {
                    const int row = t;
                    const int idx = sIc[uu * 64 + row];
                    const int lq = 2 * uu + (row >> 5);
                    const float* pp = xyz + ((size_t)batch * NPTS + idx) * 3;
                    const float dx = pp[0] - nqc[lq * 3];
                    const float dy = pp[1] - nqc[lq * 3 + 1];
                    const float dz = pp[2] - nqc[lq * 3 + 2];
                    aHi[row * 52 + 32] = pkhi(dx, dy);
                    aHi[row * 52 + 33] = pkhi(dz, 0.0f);
                    aLo[row * 52 + 32] = pklo(dx, dy);
                    aLo[row * 52 + 33] = pklo(dz, 0.0f);
                }
#pragma unroll
                for (int j = 0; j < 4; ++j) {
                    const int id = j * 256 + t;
                    const int row = id >> 4, c = 34 + (id & 15);
                    aHi[row * 52 + c] = 0u;
                    aLo[row * 52 + c] = 0u;
                }

                bf16x8 w0h[3], w0l[3];
#pragma unroll
                for (int kt = 0; kt < 3; ++kt) {
#pragma unroll
                    for (int j = 0; j < 8; ++j) {
                        const int k = kt * 32 + kb + j;
                        const int worig = (k < 64) ? (k + 3) : ((k < 67) ? (k - 64) : -1);
                        const float v = (worig >= 0) ? w0[worig * 64 + col0] : 0.0f;
                        const unsigned short h = f2bf(v);
                        w0h[kt][j] = (short)h;
                        w0l[kt][j] = (short)f2bf(v - bf2f(h));
                    }
                }
                const float bias0 = b0[col0];
                __syncthreads();

#pragma unroll
                for (int mt = 0; mt < 4; ++mt) {
                    f32x4 acc = { bias0, bias0, bias0, bias0 };
#pragma unroll
                    for (int kt = 0; kt < 3; ++kt) {
                        const int base = (mt * 16 + (lane & 15)) * 52 + kt * 16 + ((lane >> 4) << 2);
                        const bf16x8 ah = *(const bf16x8*)&aHi[base];
                        const bf16x8 al = *(const bf16x8*)&aLo[base];
                        acc = MFMA16(ah, w0h[kt], acc);
                        acc = MFMA16(al, w0h[kt], acc);
                        acc = MFMA16(ah, w0l[kt], acc);
                    }
#pragma unroll
                    for (int r = 0; r < 4; ++r) {
                        const float v = fmaxf(acc[r], 0.0f);
                        const int row = mt * 16 + ((lane >> 4) << 2) + r;
                        const unsigned short h = f2bf(v);
                        ((unsigned short*)bHi)[row * 72 + col0] = h;
                        ((unsigned short*)bLo)[row * 72 + col0] = f2bf(v - bf2f(h));
                    }
                }

                bf16x8 w1h[2], w1l[2];
#pragma unroll
                for (int kt = 0; kt < 2; ++kt) {
#pragma unroll
                    for (int j = 0; j < 8; ++j) {
                        const int k = kt * 32 + kb + j;
                        const float v = w1[k * 64 + col0];
                        const unsigned short h = f2bf(v);
                        w1h[kt][j] = (short)h;
                        w1l[kt][j] = (short)f2bf(v - bf2f(h));
                    }
                }
                const float bias1 = b1[col0];
                __syncthreads();

#pragma unroll
                for (int mt = 0; mt < 4; ++mt) {
                    f32x4 acc = { bias1, bias1, bias1, bias1 };
#pragma unroll
                    for (int kt = 0; kt < 2; ++kt) {
                        const int base = (mt * 16 + (lane & 15)) * 36 + kt * 16 + ((lane >> 4) << 2);
                        const bf16x8 ah = *(const bf16x8*)&bHi[base];
                        const bf16x8 al = *(const bf16x8*)&bLo[base];
                        acc = MFMA16(ah, w1h[kt], acc);
                        acc = MFMA16(al, w1h[kt], acc);
                        acc = MFMA16(ah, w1l[kt], acc);
                    }
#pragma unroll
                    for (int r = 0; r < 4; ++r) {
                        const float v = fmaxf(acc[r], 0.0f);
                        const int row = mt * 16 + ((lane >> 4) << 2) + r;
                        const unsigned short h = f2bf(v);
                        ((unsigned short*)aHi)[row * 72 + col0] = h;
                        ((unsigned short*)aLo)[row * 72 + col0] = f2bf(v - bf2f(h));
                    }
                }

                const int colB = ((wv + 4) << 4) + (lane & 15);
                bf16x8 w2ha[2], w2la[2], w2hb[2], w2lb[2];
#pragma unroll
                for (int kt = 0; kt < 2; ++kt) {
#pragma unroll
                    for (int j = 0; j < 8; ++j) {
                        const int k = kt * 32 + kb + j;
                        float v = w2[k * 128 + col0];
                        unsigned short h = f2bf(v);
                        w2ha[kt][j] = (short)h;
                        w2la[kt][j] = (short)f2bf(v - bf2f(h));
                        v = w2[k * 128 + colB];
                        h = f2bf(v);
                        w2hb[kt][j] = (short)h;
                        w2lb[kt][j] = (short)f2bf(v - bf2f(h));
                    }
                }
                const float bias2a = b2[col0];
                const float bias2b = b2[colB];
                __syncthreads();

#pragma unroll
                for (int gj = 0; gj < 2; ++gj) {
                    f32x4 aA[2], aB[2];
#pragma unroll
                    for (int hh = 0; hh < 2; ++hh) {
                        const int mt = gj * 2 + hh;
                        f32x4 accA = { bias2a, bias2a, bias2a, bias2a };
                        f32x4 accB = { bias2b, bias2b, bias2b, bias2b };
#pragma unroll
                        for (int kt = 0; kt < 2; ++kt) {
                            const int base = (mt * 16 + (lane & 15)) * 36 + kt * 16 + ((lane >> 4) << 2);
                            const bf16x8 ah = *(const bf16x8*)&aHi[base];
                            const bf16x8 al = *(const bf16x8*)&aLo[base];
                            accA = MFMA16(ah, w2ha[kt], accA);
                            accA = MFMA16(al, w2ha[kt], accA);
                            accA = MFMA16(ah, w2la[kt], accA);
                            accB = MFMA16(ah, w2hb[kt], accB);
                            accB = MFMA16(al, w2hb[kt], accB);
                            accB = MFMA16(ah, w2lb[kt], accB);
                        }
                        aA[hh] = accA;
                        aB[hh] = accB;
                    }
                    float mA = max3f(max3f(aA[0][0], aA[0][1], aA[0][2]),
                                     max3f(aA[0][3], aA[1][0], aA[1][1]),
                                     fmaxf(aA[1][2], aA[1][3]));
                    float mB = max3f(max3f(aB[0][0], aB[0][1], aB[0][2]),
                                     max3f(aB[0][3], aB[1][0], aB[1][1]),
                                     fmaxf(aB[1][2], aB[1][3]));
                    mA = fmaxf(mA, __shfl_xor(mA, 16));
                    mA = fmaxf(mA, __shfl_xor(mA, 32));
                    mB = fmaxf(mB, __shfl_xor(mB, 16));
                    mB = fmaxf(mB, __shfl_xor(mB, 32));
                    mA = fmaxf(mA, 0.0f);
                    mB = fmaxf(mB, 0.0f);
                    float* op = outpts + (size_t)((size_t)batch * NS + s0 + 2 * uu + gj) * 128;
                    if (lane < 16) {
                        op[(wv << 4) + lane] = mA;
                        op[((wv + 4) << 4) + lane] = mB;
                    }
                }
            }
        }
    }
}

extern "C" void kernel_launch(void* const* d_in, const int* in_sizes, int n_in,
                              void* d_out, int out_size, void* d_ws, size_t ws_size,
                              hipStream_t stream) {
    const float* xyz    = (const float*)d_in[0];
    const float* points = (const float*)d_in[1];
    const float* w0 = (const float*)d_in[2];
    const float* b0 = (const float*)d_in[3];
    const float* w1 = (const float*)d_in[4];
    const float* b1 = (const float*)d_in[5];
    const float* w2 = (const float*)d_in[6];
    const float* b2 = (const float*)d_in[7];

    unsigned* progress = (unsigned*)d_ws;  // 16 u32 counters
    hipMemsetAsync(progress, 0, 64, stream);

    fused_kernel<<<256, 256, 0, stream>>>(xyz, points, w0, b0, w1, b1, w2, b2,
                                          (float*)d_out, progress);
}